// Round 1
// baseline (578.370 us; speedup 1.0000x reference)
//
#include <hip/hip_runtime.h>
#include <hip/hip_bf16.h>
#include <math.h>

#define BB 16
#define DD 128
#define NN 4096
#define KK 1024

// ---------------------------------------------------------------------------
// Kernel A: e2[k] = ||emb[k]||^2  (f32, tiny)
// ---------------------------------------------------------------------------
__global__ void emb_sq_kernel(const float* __restrict__ emb,
                              float* __restrict__ e2) {
    int k = blockIdx.x * 256 + threadIdx.x;
    if (k >= KK) return;
    const float4* row = reinterpret_cast<const float4*>(emb + (size_t)k * DD);
    float a0 = 0.f, a1 = 0.f, a2 = 0.f, a3 = 0.f;
#pragma unroll
    for (int i = 0; i < DD / 16; ++i) {
        float4 v0 = row[i * 4 + 0];
        float4 v1 = row[i * 4 + 1];
        float4 v2 = row[i * 4 + 2];
        float4 v3 = row[i * 4 + 3];
        a0 += v0.x * v0.x + v0.y * v0.y + v0.z * v0.z + v0.w * v0.w;
        a1 += v1.x * v1.x + v1.y * v1.y + v1.z * v1.z + v1.w * v1.w;
        a2 += v2.x * v2.x + v2.y * v2.y + v2.z * v2.z + v2.w * v2.w;
        a3 += v3.x * v3.x + v3.y * v3.y + v3.z * v3.z + v3.w * v3.w;
    }
    e2[k] = (a0 + a1) + (a2 + a3);
}

// ---------------------------------------------------------------------------
// Main kernel: per block = one (b, 64-column n-tile).
//   - lane owns column n0+lane: full ze column in 128 VGPRs
//   - 4 waves split K (256 codewords each), emb rows via wave-uniform s_loads
//   - per-lane top-2 (min,2nd-min) of m = ||e_k||^2 - 2<ze,e_k>
//   - cross-wave merge in LDS, f64 exact refine when gap < TAU
//   - coalesced epilogue: winner rows staged in LDS (pad 129 -> no conflicts)
// ---------------------------------------------------------------------------
__global__ __launch_bounds__(256, 2)
void vq_main(const float* __restrict__ ze, const float* __restrict__ emb,
             const float* __restrict__ e2, float* __restrict__ out) {
    const int lane = threadIdx.x & 63;
    const int wave = threadIdx.x >> 6;
    const int tile = blockIdx.x;        // 0..1023
    const int b    = tile >> 6;         // 64 tiles per batch entry
    const int n0   = (tile & 63) * 64;
    const int n    = n0 + lane;
    const float* zb = ze + (size_t)b * DD * NN;

    // ze column in registers (statically indexed everywhere -> stays in VGPRs)
    float z[DD];
#pragma unroll
    for (int d = 0; d < DD; ++d) z[d] = zb[d * NN + n];

    float m1 = INFINITY, m2 = INFINITY;
    int   i1 = 0,        i2 = 0;
    const int k0 = __builtin_amdgcn_readfirstlane(wave) * 256;  // force SGPR

#pragma unroll 2
    for (int kk = 0; kk < 256; ++kk) {
        const int k = k0 + kk;                  // wave-uniform
        const float* er = emb + k * DD;         // uniform -> s_load rows
        float a0 = 0.f, a1 = 0.f, a2 = 0.f, a3 = 0.f;
#pragma unroll
        for (int d = 0; d < DD; d += 4) {
            a0 = fmaf(er[d + 0], z[d + 0], a0);
            a1 = fmaf(er[d + 1], z[d + 1], a1);
            a2 = fmaf(er[d + 2], z[d + 2], a2);
            a3 = fmaf(er[d + 3], z[d + 3], a3);
        }
        const float dot = (a0 + a1) + (a2 + a3);
        const float m   = fmaf(-2.0f, dot, e2[k]);
        // top-2 update, strict < keeps earliest k on exact ties
        if (m < m2) {
            if (m < m1) { m2 = m1; i2 = i1; m1 = m; i1 = k; }
            else        { m2 = m;  i2 = k; }
        }
    }

    // ---- cross-wave top-2 merge ----
    __shared__ float sm[4][2][64];
    __shared__ int   si[4][2][64];
    __shared__ int   winner[64];
    sm[wave][0][lane] = m1; sm[wave][1][lane] = m2;
    si[wave][0][lane] = i1; si[wave][1][lane] = i2;
    __syncthreads();

    if (threadIdx.x < 64) {
        const int c = lane;
        float M1 = INFINITY, M2 = INFINITY;
        int   I1 = 0,        I2 = 0;
#pragma unroll
        for (int w = 0; w < 4; ++w) {
#pragma unroll
            for (int j = 0; j < 2; ++j) {
                const float m = sm[w][j][c];
                const int   i = si[w][j][c];
                if (m < M2) {
                    if (m < M1) { M2 = M1; I2 = I1; M1 = m; I1 = i; }
                    else        { M2 = m;  I2 = i; }
                }
            }
        }
        // exact f64 re-compare when approx gap could hide an argmin flip.
        // f32 worst-case error on m is ~1e-3 << TAU, so every possible flip
        // lands in this branch. Trigger rate ~1e-3 of positions.
        if (M2 - M1 < 1e-2f) {
            const float* ea = emb + I1 * DD;
            const float* eb = emb + I2 * DD;
            double d2a = 0.0, d2b = 0.0;
#pragma unroll
            for (int d = 0; d < DD; ++d) {   // full unroll: z[] stays in regs
                const double da = (double)z[d] - (double)ea[d];
                const double db = (double)z[d] - (double)eb[d];
                d2a += da * da;
                d2b += db * db;
            }
            if (d2b < d2a || (d2b == d2a && I2 < I1)) I1 = I2;
        }
        winner[c] = I1;
    }
    __syncthreads();

    // ---- epilogue: stage the 64 winner rows into LDS (coalesced reads) ----
    __shared__ float ew[64][DD + 1];   // pad -> stride 129 words, conflict-free
#pragma unroll 4
    for (int r = wave * 16; r < wave * 16 + 16; ++r) {
        const int idx = winner[r];             // wave-uniform per iteration
        ew[r][lane]      = emb[idx * DD + lane];
        ew[r][lane + 64] = emb[idx * DD + lane + 64];
    }
    __syncthreads();

    // coalesced output: out = ze + (zq - ze), matching reference f32 ordering
#pragma unroll 4
    for (int dd = 0; dd < 32; ++dd) {
        const int d  = wave * 32 + dd;
        const float zv = zb[d * NN + n0 + lane];
        const float ev = ew[lane][d];
        out[((size_t)b * DD + d) * NN + n0 + lane] = zv + (ev - zv);
    }
}

// ---------------------------------------------------------------------------
extern "C" void kernel_launch(void* const* d_in, const int* in_sizes, int n_in,
                              void* d_out, int out_size, void* d_ws, size_t ws_size,
                              hipStream_t stream) {
    (void)in_sizes; (void)n_in; (void)out_size; (void)ws_size;
    const float* ze  = (const float*)d_in[0];   // (B, D, N) f32
    const float* emb = (const float*)d_in[1];   // (K, D)    f32
    float*       out = (float*)d_out;           // (B, D, N) f32
    float*       e2  = (float*)d_ws;            // K floats scratch

    emb_sq_kernel<<<KK / 256, 256, 0, stream>>>(emb, e2);
    vq_main<<<(BB * NN) / 64, 256, 0, stream>>>(ze, emb, e2, out);
}

// Round 2
// 116.892 us; speedup vs baseline: 4.9479x; 4.9479x over previous
//
#include <hip/hip_runtime.h>
#include <hip/hip_bf16.h>
#include <math.h>

#define BB 16
#define DD 128
#define NN 4096
#define KK 1024

typedef __attribute__((ext_vector_type(8))) short short8;
typedef __attribute__((ext_vector_type(4))) float f32x4;

__device__ __forceinline__ unsigned short f32_bf16_rne(float f) {
    unsigned u = __float_as_uint(f);
    u += 0x7FFF + ((u >> 16) & 1);
    return (unsigned short)(u >> 16);
}
__device__ __forceinline__ float bf16_f32(unsigned short h) {
    return __uint_as_float(((unsigned)h) << 16);
}

// ---------------------------------------------------------------------------
// e2[k] = ||emb[k]||^2  (f32)
// ---------------------------------------------------------------------------
__global__ void emb_sq_kernel(const float* __restrict__ emb,
                              float* __restrict__ e2) {
    int k = blockIdx.x * 256 + threadIdx.x;
    if (k >= KK) return;
    const float4* row = reinterpret_cast<const float4*>(emb + (size_t)k * DD);
    float a0 = 0.f, a1 = 0.f, a2 = 0.f, a3 = 0.f;
#pragma unroll
    for (int i = 0; i < DD / 16; ++i) {
        float4 v0 = row[i * 4 + 0];
        float4 v1 = row[i * 4 + 1];
        float4 v2 = row[i * 4 + 2];
        float4 v3 = row[i * 4 + 3];
        a0 += v0.x * v0.x + v0.y * v0.y + v0.z * v0.z + v0.w * v0.w;
        a1 += v1.x * v1.x + v1.y * v1.y + v1.z * v1.z + v1.w * v1.w;
        a2 += v2.x * v2.x + v2.y * v2.y + v2.z * v2.z + v2.w * v2.w;
        a3 += v3.x * v3.x + v3.y * v3.y + v3.z * v3.z + v3.w * v3.w;
    }
    e2[k] = (a0 + a1) + (a2 + a3);
}

// ---------------------------------------------------------------------------
// Pack emb into MFMA A-fragment order, split into bf16 hi + lo.
// Fragment (t, s, lane) holds 8 bf16: emb[k = t*16 + (lane&15)]
//                                        [d = s*32 + (lane>>4)*8 + j], j=0..7
// stored at offset ((t*4+s)*64 + lane)*8 elements -> main-loop wave loads are
// 64 lanes x 16B = 1KB perfectly coalesced, L2-resident (2x256KB total).
// ---------------------------------------------------------------------------
__global__ void emb_pack_kernel(const float* __restrict__ emb,
                                short* __restrict__ ehi,
                                short* __restrict__ elo) {
    int g = blockIdx.x * 256 + threadIdx.x;     // 16384 fragments
    int lane = g & 63;
    int s    = (g >> 6) & 3;
    int t    = g >> 8;
    int k = t * 16 + (lane & 15);
    int d = s * 32 + ((lane >> 4) & 3) * 8;
    const float* src = emb + (size_t)k * DD + d;
    short8 h, l;
#pragma unroll
    for (int j = 0; j < 8; ++j) {
        float z = src[j];
        unsigned short hb = f32_bf16_rne(z);
        float hf = bf16_f32(hb);
        unsigned short lb = f32_bf16_rne(z - hf);
        h[j] = (short)hb;
        l[j] = (short)lb;
    }
    *reinterpret_cast<short8*>(ehi + (size_t)g * 8) = h;
    *reinterpret_cast<short8*>(elo + (size_t)g * 8) = l;
}

// ---------------------------------------------------------------------------
// Main: block = (b, 64-column n-tile); wave w owns 16 columns x all 1024 k.
// dot via 3-term bf16-split MFMA (zh*eh + zh*el + zl*eh), f32 accumulate.
// m[k,n] = e2[k] - 2*dot. Per-lane top-2 over k, shfl merge, f64 exact refine
// when gap < TAU (catches every possible argmin flip; trigger ~2e-3).
// No LDS / barriers in the main loop.
// ---------------------------------------------------------------------------
__global__ __launch_bounds__(256)
void vq_mfma(const float* __restrict__ ze, const float* __restrict__ emb,
             const short* __restrict__ ehi, const short* __restrict__ elo,
             const float* __restrict__ e2, float* __restrict__ out) {
    const int lane = threadIdx.x & 63;
    const int wave = threadIdx.x >> 6;
    const int tile = blockIdx.x;          // 0..1023
    const int b    = tile >> 6;
    const int n0   = (tile & 63) * 64;
    const float* zb = ze + (size_t)b * DD * NN;

    const int nq = lane & 15;             // column within wave's 16
    const int dq = (lane >> 4) & 3;       // k-dim sub-group
    const int mycol = n0 + wave * 16 + nq;

    // ---- B-fragments: ze column slice, bf16 hi/lo split (32 VGPRs) ----
    short8 zh[4], zl[4];
#pragma unroll
    for (int s = 0; s < 4; ++s) {
#pragma unroll
        for (int j = 0; j < 8; ++j) {
            int d = s * 32 + dq * 8 + j;
            float z = zb[(size_t)d * NN + mycol];
            unsigned short hb = f32_bf16_rne(z);
            float hf = bf16_f32(hb);
            unsigned short lb = f32_bf16_rne(z - hf);
            zh[s][j] = (short)hb;
            zl[s][j] = (short)lb;
        }
    }

    float m1 = INFINITY, m2 = INFINITY;
    int   i1 = 0,        i2 = 0;

    for (int t4 = 0; t4 < 16; ++t4) {     // 4 k-tiles (64 codewords) per iter
        f32x4 acc[4] = {{0.f,0.f,0.f,0.f},{0.f,0.f,0.f,0.f},
                        {0.f,0.f,0.f,0.f},{0.f,0.f,0.f,0.f}};
#pragma unroll
        for (int s = 0; s < 4; ++s) {
#pragma unroll
            for (int tt = 0; tt < 4; ++tt) {
                size_t fo = ((size_t)((t4 * 4 + tt) * 4 + s) * 64 + lane) * 8;
                short8 ah = *reinterpret_cast<const short8*>(ehi + fo);
                short8 al = *reinterpret_cast<const short8*>(elo + fo);
                acc[tt] = __builtin_amdgcn_mfma_f32_16x16x32_bf16(ah, zh[s], acc[tt], 0, 0, 0);
                acc[tt] = __builtin_amdgcn_mfma_f32_16x16x32_bf16(al, zh[s], acc[tt], 0, 0, 0);
                acc[tt] = __builtin_amdgcn_mfma_f32_16x16x32_bf16(ah, zl[s], acc[tt], 0, 0, 0);
            }
        }
#pragma unroll
        for (int tt = 0; tt < 4; ++tt) {
            int t = t4 * 4 + tt;
            float4 ev = *reinterpret_cast<const float4*>(e2 + t * 16 + dq * 4);
            float evr[4] = {ev.x, ev.y, ev.z, ev.w};
#pragma unroll
            for (int r = 0; r < 4; ++r) {
                float m = fmaf(-2.0f, acc[tt][r], evr[r]);
                int k = t * 16 + dq * 4 + r;   // C/D: row=(lane>>4)*4+r, col=lane&15
                if (m < m2) {
                    if (m < m1) { m2 = m1; i2 = i1; m1 = m; i1 = k; }
                    else        { m2 = m;  i2 = k; }
                }
            }
        }
    }

    // ---- merge top-2 across the 4 dq lane-groups (same n = lane&15) ----
#pragma unroll
    for (int off = 16; off < 64; off <<= 1) {
        float om1 = __shfl_xor(m1, off);
        int   oi1 = __shfl_xor(i1, off);
        float om2 = __shfl_xor(m2, off);
        int   oi2 = __shfl_xor(i2, off);
        float M1, M2; int I1, I2;
        bool ofirst = (om1 < m1) || (om1 == m1 && oi1 < i1);
        if (ofirst) {
            M1 = om1; I1 = oi1;
            if ((m1 < om2) || (m1 == om2 && i1 < oi2)) { M2 = m1; I2 = i1; }
            else                                       { M2 = om2; I2 = oi2; }
        } else {
            M1 = m1; I1 = i1;
            if ((om1 < m2) || (om1 == m2 && oi1 < i2)) { M2 = om1; I2 = oi1; }
            else                                       { M2 = m2; I2 = i2; }
        }
        m1 = M1; i1 = I1; m2 = M2; i2 = I2;
    }

    __shared__ int   winner[64];
    __shared__ float ew[64][DD + 1];

    if (lane < 16) {
        int n = n0 + wave * 16 + lane;
        int w1 = i1;
        // exact f64 re-compare when approx gap could hide an argmin flip.
        // bf16-split dot error ~3e-3 << TAU/2, so every flip lands here.
        if (m2 - m1 < 2e-2f) {
            const float* ea = emb + (size_t)i1 * DD;
            const float* eb = emb + (size_t)i2 * DD;
            double d2a = 0.0, d2b = 0.0;
            for (int d = 0; d < DD; ++d) {
                double zv = (double)zb[(size_t)d * NN + n];
                double da = zv - (double)ea[d];
                double db = zv - (double)eb[d];
                d2a += da * da;
                d2b += db * db;
            }
            if (d2b < d2a || (d2b == d2a && i2 < i1)) w1 = i2;
        }
        winner[wave * 16 + lane] = w1;
    }
    __syncthreads();

    // ---- epilogue: stage winner rows in LDS, write coalesced (round-1) ----
#pragma unroll 4
    for (int r = wave * 16; r < wave * 16 + 16; ++r) {
        const int idx = winner[r];              // wave-uniform per iteration
        ew[r][lane]      = emb[(size_t)idx * DD + lane];
        ew[r][lane + 64] = emb[(size_t)idx * DD + lane + 64];
    }
    __syncthreads();

#pragma unroll 4
    for (int dd = 0; dd < 32; ++dd) {
        const int d  = wave * 32 + dd;
        const float zv = zb[(size_t)d * NN + n0 + lane];
        const float evv = ew[lane][d];
        out[((size_t)b * DD + d) * NN + n0 + lane] = zv + (evv - zv);
    }
}

// ---------------------------------------------------------------------------
extern "C" void kernel_launch(void* const* d_in, const int* in_sizes, int n_in,
                              void* d_out, int out_size, void* d_ws, size_t ws_size,
                              hipStream_t stream) {
    (void)in_sizes; (void)n_in; (void)out_size; (void)ws_size;
    const float* ze  = (const float*)d_in[0];   // (B, D, N) f32
    const float* emb = (const float*)d_in[1];   // (K, D)    f32
    float*       out = (float*)d_out;           // (B, D, N) f32

    char* ws = (char*)d_ws;
    short* ehi = (short*)ws;                          // 256 KB
    short* elo = (short*)(ws + (size_t)KK * DD * 2);  // 256 KB
    float* e2  = (float*)(ws + (size_t)KK * DD * 4);  // 4 KB

    emb_sq_kernel<<<KK / 256, 256, 0, stream>>>(emb, e2);
    emb_pack_kernel<<<(KK * DD / 8) / 256, 256, 0, stream>>>(emb, ehi, elo);
    vq_mfma<<<(BB * NN) / 64, 256, 0, stream>>>(ze, emb, ehi, elo, e2, out);
}